// Round 2
// baseline (231.634 us; speedup 1.0000x reference)
//
#include <hip/hip_runtime.h>
#include <math.h>

// Problem constants: im [16,3,512,960] f32, disp [16,1,512,960] f32, disp in [0,40).
#define B_ 16
#define C_ 3
#define H_ 512
#define W_ 960
constexpr int HW = H_ * W_;
constexpr float EPS_ = 1e-6f;
constexpr float LOG2_BASE = 0.49978213f;  // log2(1.414)

typedef __attribute__((ext_vector_type(2))) float f2;
typedef __attribute__((ext_vector_type(4))) float f4v;

// ---------------------------------------------------------------------------
// GATHER formulation: target t receives from sources x in [t, t+T+39] with
// tent weight bw = max(0, 1 - |(x - d(x)) - t|) — identical to the
// reference's bilinear scatter incl. boundary validity. disp.min()
// subtraction is a global scale on wmap that cancels in res (|effect|~2e-6)
// and is dropped.
//
// r5 (this round): T=4 -> T=8 targets/thread. rocprof r4: VALUBusy 72%,
// conflicts 0, occupancy 58% -> DS pipe is the larger floor (44 cand x
// ~18 cyc x 120 waves/CU ~ 40us vs VALU ~26us). T=8 cuts DS reads/target
// 11 -> 6 (-45%) for +9% pair-tests, and doubles VALU insts between DS
// reads (better intra-wave hiding). 128-thread blocks, 1 row each;
// LDS 8 phases x 125 slots x 20B = 20000B -> exactly 8 blocks/CU
// (16 waves/CU cap; accepted tradeoff vs halved DS traffic).
__global__ __launch_bounds__(128, 4) void splat_kernel(const float* __restrict__ im,
                                                       const float* __restrict__ disp,
                                                       float* __restrict__ out) {
    constexpr int SLOTS = 125;        // 120 real (x = 8s+p <= 959) + 5 sentinel
    __shared__ float  txS[8 * SLOTS]; // tx = x - d, phase p = x&7, slot x>>3
    __shared__ float4 fS [8 * SLOTS]; // {v0*w, v1*w, v2*w, w}

    const int row = blockIdx.x;       // b*H + y
    const int b   = row >> 9;         // H_ == 512
    const int y   = row & (H_ - 1);
    const int rowoff = row * W_;
    const float* imr = im + (size_t)b * C_ * HW + (size_t)y * W_;
    const int tid = threadIdx.x;

    // ---- sentinels: slots 120..124 of each phase (candidate x reaches 999)
    if (tid < 40) {
        const int p = tid / 5, s = 120 + tid % 5;
        txS[p * SLOTS + s] = -1.0e9f;                   // tent weight -> 0
        fS [p * SLOTS + s] = make_float4(0.f, 0.f, 0.f, 0.f);
    }

    // ---- stage: 240 chunks of 4 px, float4 loads (contiguous per inst)
    for (int i = tid; i < 240; i += 128) {
        const int x0 = 4 * i;
        f4v d4 = *(const f4v*)(disp + rowoff + x0);
        f4v c0 = *(const f4v*)(imr + x0);
        f4v c1 = *(const f4v*)(imr + HW + x0);
        f4v c2 = *(const f4v*)(imr + 2 * HW + x0);
        #pragma unroll
        for (int k = 0; k < 4; ++k) {
            const int x = x0 + k;
            const int p = x & 7, s = x >> 3;
            float d = d4[k];
            float w = exp2f(d * LOG2_BASE);             // unshifted: scale cancels
            txS[p * SLOTS + s] = (float)x - d;
            fS [p * SLOTS + s] = make_float4(c0[k] * w, c1[k] * w, c2[k] * w, w);
        }
    }
    __syncthreads();

    // ---- gather: threads 0..119 own targets 8*tid .. 8*tid+7
    if (tid >= 120) return;

    const float t0 = (float)(8 * tid);
    f2 T0[4], A0[4], A1[4], A2[4], AW[4], AC[4];
    #pragma unroll
    for (int q = 0; q < 4; ++q) {
        T0[q] = (f2){t0 + (float)(2 * q), t0 + (float)(2 * q + 1)};
        A0[q] = 0.f; A1[q] = 0.f; A2[q] = 0.f; AW[q] = 0.f; AC[q] = 0.f;
    }

    // candidate x = 8*tid + 8*c + p (j = 8c+p in [0,47]); phase p row,
    // slot tid + c: consecutive slots across lanes -> 2-way max (free).
    #pragma unroll
    for (int p = 0; p < 8; ++p) {
        const float*  txrow = &txS[p * SLOTS + tid];
        const float4* frow  = &fS [p * SLOTS + tid];
        #pragma unroll
        for (int c = 0; c < 6; ++c) {
            float  txv = txrow[c];
            float4 f   = frow[c];
            const f2 txv2 = {txv, txv};
            #pragma unroll
            for (int q = 0; q < 4; ++q) {
                f2 e = txv2 - T0[q];                    // {tx-(t0+2q), tx-(t0+2q+1)}
                f2 w;
                w.x = __builtin_fmaxf(1.0f - __builtin_fabsf(e.x), 0.0f);
                w.y = __builtin_fmaxf(1.0f - __builtin_fabsf(e.y), 0.0f);
                A0[q] += f.x * w;
                A1[q] += f.y * w;
                A2[q] += f.z * w;
                AW[q] += f.w * w;
                AC[q] += w;
            }
        }
    }

    // ---- epilogue: v_rcp (rel err ~1e-7, tolerance 2e-2), float4 stores
    float i0 = __builtin_amdgcn_rcpf(__builtin_fmaxf(AW[0].x, EPS_));
    float i1 = __builtin_amdgcn_rcpf(__builtin_fmaxf(AW[0].y, EPS_));
    float i2 = __builtin_amdgcn_rcpf(__builtin_fmaxf(AW[1].x, EPS_));
    float i3 = __builtin_amdgcn_rcpf(__builtin_fmaxf(AW[1].y, EPS_));
    float i4 = __builtin_amdgcn_rcpf(__builtin_fmaxf(AW[2].x, EPS_));
    float i5 = __builtin_amdgcn_rcpf(__builtin_fmaxf(AW[2].y, EPS_));
    float i6 = __builtin_amdgcn_rcpf(__builtin_fmaxf(AW[3].x, EPS_));
    float i7 = __builtin_amdgcn_rcpf(__builtin_fmaxf(AW[3].y, EPS_));

    float* o0 = out + (size_t)b * C_ * HW + (size_t)y * W_ + 8 * tid;
    *(float4*)(o0)              = make_float4(A0[0].x * i0, A0[0].y * i1, A0[1].x * i2, A0[1].y * i3);
    *(float4*)(o0 + 4)          = make_float4(A0[2].x * i4, A0[2].y * i5, A0[3].x * i6, A0[3].y * i7);
    *(float4*)(o0 + HW)         = make_float4(A1[0].x * i0, A1[0].y * i1, A1[1].x * i2, A1[1].y * i3);
    *(float4*)(o0 + HW + 4)     = make_float4(A1[2].x * i4, A1[2].y * i5, A1[3].x * i6, A1[3].y * i7);
    *(float4*)(o0 + 2 * HW)     = make_float4(A2[0].x * i0, A2[0].y * i1, A2[1].x * i2, A2[1].y * i3);
    *(float4*)(o0 + 2 * HW + 4) = make_float4(A2[2].x * i4, A2[2].y * i5, A2[3].x * i6, A2[3].y * i7);

    float* oc = out + (size_t)B_ * C_ * HW + (size_t)rowoff + 8 * tid;
    *(float4*)(oc)     = make_float4(1.0f - __builtin_fminf(AC[0].x, 1.0f),
                                     1.0f - __builtin_fminf(AC[0].y, 1.0f),
                                     1.0f - __builtin_fminf(AC[1].x, 1.0f),
                                     1.0f - __builtin_fminf(AC[1].y, 1.0f));
    *(float4*)(oc + 4) = make_float4(1.0f - __builtin_fminf(AC[2].x, 1.0f),
                                     1.0f - __builtin_fminf(AC[2].y, 1.0f),
                                     1.0f - __builtin_fminf(AC[3].x, 1.0f),
                                     1.0f - __builtin_fminf(AC[3].y, 1.0f));
}

// ---------------------------------------------------------------------------
extern "C" void kernel_launch(void* const* d_in, const int* in_sizes, int n_in,
                              void* d_out, int out_size, void* d_ws, size_t ws_size,
                              hipStream_t stream) {
    (void)in_sizes; (void)n_in; (void)out_size; (void)d_ws; (void)ws_size;
    const float* im   = (const float*)d_in[0];
    const float* disp = (const float*)d_in[1];
    float* out        = (float*)d_out;

    splat_kernel<<<B_ * H_, 128, 0, stream>>>(im, disp, out);
}